// Round 14
// baseline (146.163 us; speedup 1.0000x reference)
//
#include <hip/hip_runtime.h>
#include <hip/hip_bf16.h>

#define N_USERS 100000
#define N_ITEMS 50000
#define NNZ_EDGES 1600000
#define DIM 64

#define BSHIFT_U 8
#define BD_U 256                             // user dests per coarse bucket
#define BSHIFT_I 7
#define BD_I 128                             // item dests per coarse bucket
#define NBU ((N_USERS + BD_U - 1) / BD_U)    // 391
#define NBI ((N_ITEMS + BD_I - 1) / BD_I)    // 391
#define NB_MAX 391
#define TILE 4096                            // edges per binning tile (4/thread @1024)
#define CAP 4608                             // bucket capacity (mean 4096 + 8 sigma)
#define GEMM_BLKS_U ((N_USERS + 63) / 64)    // 1563
#define GEMM_BLKS_I ((N_ITEMS + 63) / 64)    // 782

// Record layout: pk = (dst_local << 24) | (src << 6). src<<6 <= 23 bits,
// dst_local <= 8 bits. Gather element index = (pk & 0xFFFFC0) + feature.

__device__ inline unsigned short f32_to_bf16(float f) {
  unsigned u = __float_as_uint(f);
  unsigned r = (u + 0x7FFFu + ((u >> 16) & 1u)) >> 16;  // RNE
  return (unsigned short)r;
}

// ---------------------------------------------------------------------------
// Merged dense GEMM (both projections). Block 0 also seeds bucket cursors.
// ---------------------------------------------------------------------------
__global__ __launch_bounds__(256) void gemm_both_kernel(
    const float* __restrict__ Xu, const float* __restrict__ Wu,
    unsigned short* __restrict__ Yu,
    const float* __restrict__ Xi, const float* __restrict__ Wi,
    unsigned short* __restrict__ Yi,
    int* __restrict__ cur_u, int* __restrict__ cur_i) {
  __shared__ float sXT[64][64];   // [k][row]
  __shared__ float sW[64][64];    // [k][col]
  const int tid = threadIdx.x;

  if (blockIdx.x == 0) {
    for (int t = tid; t < NBU; t += 256) cur_u[t] = t * CAP;
    for (int t = tid; t < NBI; t += 256) cur_i[t] = t * CAP;
  }

  const float* X; const float* W; unsigned short* Y; int nrows, row_base;
  if (blockIdx.x < GEMM_BLKS_U) {
    X = Xu; W = Wu; Y = Yu; nrows = N_USERS; row_base = blockIdx.x * 64;
  } else {
    X = Xi; W = Wi; Y = Yi; nrows = N_ITEMS; row_base = (blockIdx.x - GEMM_BLKS_U) * 64;
  }

  {
    const float4* Wv = (const float4*)W;
    float4* sWv = (float4*)&sW[0][0];
    #pragma unroll
    for (int i = 0; i < 4; ++i) sWv[tid + i * 256] = Wv[tid + i * 256];
  }
  {
    const int r = tid & 63;
    const int k0 = (tid >> 6) * 16;
    const int grow = row_base + r;
    #pragma unroll
    for (int i = 0; i < 4; ++i) {
      float4 v = make_float4(0.f, 0.f, 0.f, 0.f);
      if (grow < nrows) v = ((const float4*)(X + (size_t)grow * DIM + k0))[i];
      sXT[k0 + i * 4 + 0][r] = v.x;
      sXT[k0 + i * 4 + 1][r] = v.y;
      sXT[k0 + i * 4 + 2][r] = v.z;
      sXT[k0 + i * 4 + 3][r] = v.w;
    }
  }
  __syncthreads();

  const int tx = tid & 15;
  const int ty = tid >> 4;
  float acc[4][4] = {{0.f}};

  #pragma unroll 8
  for (int k = 0; k < 64; ++k) {
    const float4 a = *(const float4*)&sXT[k][ty * 4];
    const float4 b = *(const float4*)&sW[k][tx * 4];
    acc[0][0] = fmaf(a.x, b.x, acc[0][0]);
    acc[0][1] = fmaf(a.x, b.y, acc[0][1]);
    acc[0][2] = fmaf(a.x, b.z, acc[0][2]);
    acc[0][3] = fmaf(a.x, b.w, acc[0][3]);
    acc[1][0] = fmaf(a.y, b.x, acc[1][0]);
    acc[1][1] = fmaf(a.y, b.y, acc[1][1]);
    acc[1][2] = fmaf(a.y, b.z, acc[1][2]);
    acc[1][3] = fmaf(a.y, b.w, acc[1][3]);
    acc[2][0] = fmaf(a.z, b.x, acc[2][0]);
    acc[2][1] = fmaf(a.z, b.y, acc[2][1]);
    acc[2][2] = fmaf(a.z, b.z, acc[2][2]);
    acc[2][3] = fmaf(a.z, b.w, acc[2][3]);
    acc[3][0] = fmaf(a.w, b.x, acc[3][0]);
    acc[3][1] = fmaf(a.w, b.y, acc[3][1]);
    acc[3][2] = fmaf(a.w, b.z, acc[3][2]);
    acc[3][3] = fmaf(a.w, b.w, acc[3][3]);
  }

  #pragma unroll
  for (int r = 0; r < 4; ++r) {
    const int grow = row_base + ty * 4 + r;
    if (grow < nrows) {
      ushort4 o;
      o.x = f32_to_bf16(acc[r][0]);
      o.y = f32_to_bf16(acc[r][1]);
      o.z = f32_to_bf16(acc[r][2]);
      o.w = f32_to_bf16(acc[r][3]);
      *(ushort4*)(Y + (size_t)grow * DIM + tx * 4) = o;
    }
  }
}

// ---------------------------------------------------------------------------
// Combined two-direction LDS-binning, 1024 threads (4 records/thread).
// Writes into fixed-capacity per-bucket regions (cursor base = b*CAP).
// ---------------------------------------------------------------------------
__global__ __launch_bounds__(1024) void binning2_kernel(
    const int* __restrict__ rows, const int* __restrict__ cols,
    const float* __restrict__ vals,
    int* __restrict__ cur_u, int* __restrict__ cur_i,
    uint2* __restrict__ out_u, uint2* __restrict__ out_i, int nnz) {
  __shared__ int sh[NB_MAX];          // hist -> excl -> cursor -> global base
  __shared__ int scnt[NB_MAX];        // counts -> excl
  __shared__ uint2 sbuf[TILE];        // 32 KB
  __shared__ unsigned short sbk[TILE];// 8 KB
  __shared__ int s_w[16];

  const int tid = threadIdx.x, lane = tid & 63, wid = tid >> 6;
  const int tbase = blockIdx.x * TILE;
  const int total = min(TILE, nnz - tbase);

  int er[4], ec[4]; unsigned ev[4];
  #pragma unroll
  for (int k = 0; k < 4; ++k) {
    const int i = tbase + k * 1024 + tid;
    if (i < nnz) {
      er[k] = rows[i];
      ec[k] = cols[i];
      ev[k] = __float_as_uint(vals[i]);
    } else {
      er[k] = -1; ec[k] = 0; ev[k] = 0;
    }
  }

#define BIN_PHASE(BKEXPR, PKEXPR, NB, CUR, OUT)                                \
  {                                                                            \
    for (int j = tid; j < (NB); j += 1024) sh[j] = 0;                          \
    __syncthreads();                                                           \
    int bk[4]; unsigned pk[4];                                                 \
    _Pragma("unroll")                                                          \
    for (int k = 0; k < 4; ++k) {                                              \
      if (er[k] >= 0) {                                                        \
        bk[k] = (BKEXPR); pk[k] = (PKEXPR);                                    \
        atomicAdd(&sh[bk[k]], 1);                                              \
      } else { bk[k] = -1; pk[k] = 0; }                                        \
    }                                                                          \
    __syncthreads();                                                           \
    {                                                                          \
      const int x = (tid < (NB)) ? sh[tid] : 0;                                \
      int incl = x;                                                            \
      _Pragma("unroll")                                                        \
      for (int d = 1; d < 64; d <<= 1) {                                       \
        int t = __shfl_up(incl, d);                                            \
        if (lane >= d) incl += t;                                              \
      }                                                                        \
      if (lane == 63) s_w[wid] = incl;                                         \
      __syncthreads();                                                         \
      if (tid == 0) {                                                          \
        int a = 0;                                                             \
        _Pragma("unroll")                                                      \
        for (int w = 0; w < 16; ++w) { const int t = s_w[w]; s_w[w] = a; a += t; } \
      }                                                                        \
      __syncthreads();                                                         \
      const int excl = s_w[wid] + incl - x;                                    \
      if (tid < (NB)) { scnt[tid] = x; sh[tid] = excl; }                       \
      __syncthreads();                                                         \
    }                                                                          \
    _Pragma("unroll")                                                          \
    for (int k = 0; k < 4; ++k) {                                              \
      if (bk[k] >= 0) {                                                        \
        const int p = atomicAdd(&sh[bk[k]], 1);                                \
        sbuf[p] = make_uint2(pk[k], ev[k]);                                    \
        sbk[p] = (unsigned short)bk[k];                                        \
      }                                                                        \
    }                                                                          \
    __syncthreads();                                                           \
    if (tid < (NB)) {                                                          \
      const int c = scnt[tid];                                                 \
      const int excl = sh[tid] - c;                                            \
      int g = 0;                                                               \
      if (c > 0) g = atomicAdd(&(CUR)[tid], c);                                \
      scnt[tid] = excl;                                                        \
      sh[tid] = g;                                                             \
    }                                                                          \
    __syncthreads();                                                           \
    for (int p = tid; p < total; p += 1024) {                                  \
      const int b = sbk[p];                                                    \
      (OUT)[sh[b] + (p - scnt[b])] = sbuf[p];                                  \
    }                                                                          \
    __syncthreads();                                                           \
  }

  BIN_PHASE(er[k] >> BSHIFT_U,
            ((unsigned)(er[k] & (BD_U - 1)) << 24) | ((unsigned)ec[k] << 6),
            NBU, cur_u, out_u)
  BIN_PHASE(ec[k] >> BSHIFT_I,
            ((unsigned)(ec[k] & (BD_I - 1)) << 24) | ((unsigned)er[k] << 6),
            NBI, cur_i, out_i)
#undef BIN_PHASE
}

// ---------------------------------------------------------------------------
// Merged fine sort, IN-PLACE per bucket (race-free in one dispatch).
// ---------------------------------------------------------------------------
__global__ __launch_bounds__(1024) void fine_sort_both_kernel(
    uint2* __restrict__ bin_u, const int* __restrict__ cur_u,
    int* __restrict__ uoff, int* __restrict__ uend,
    uint2* __restrict__ bin_i, const int* __restrict__ cur_i,
    int* __restrict__ ioff, int* __restrict__ iend) {
  __shared__ uint2 sbuf[CAP];     // 36.9 KB
  __shared__ int cnt[256];
  __shared__ int s_w[4];
  const int tid = threadIdx.x;
  const int lane = tid & 63, wid = tid >> 6;

  uint2* bin; const int* cur; int* roff; int* rend;
  int b, bd, ndst;
  if (blockIdx.x < NBU) {
    b = blockIdx.x; bd = BD_U; ndst = N_USERS;
    bin = bin_u; cur = cur_u; roff = uoff; rend = uend;
  } else {
    b = blockIdx.x - NBU; bd = BD_I; ndst = N_ITEMS;
    bin = bin_i; cur = cur_i; roff = ioff; rend = iend;
  }
  const int beg = b * CAP;
  const int n = min(cur[b] - beg, CAP);

  if (tid < bd) cnt[tid] = 0;
  __syncthreads();

  for (int i = tid; i < n; i += 1024) {
    const uint2 r = bin[beg + i];
    sbuf[i] = r;
    atomicAdd(&cnt[r.x >> 24], 1);
  }
  __syncthreads();

  int x = 0, incl = 0;
  if (tid < 256) {
    x = (tid < bd) ? cnt[tid] : 0;
    incl = x;
    #pragma unroll
    for (int d = 1; d < 64; d <<= 1) {
      int t = __shfl_up(incl, d);
      if (lane >= d) incl += t;
    }
    if (lane == 63) s_w[wid] = incl;
  }
  __syncthreads();
  if (tid == 0) {
    int a = 0;
    #pragma unroll
    for (int w = 0; w < 4; ++w) { const int t = s_w[w]; s_w[w] = a; a += t; }
  }
  __syncthreads();
  if (tid < 256) {
    const int excl = s_w[wid] + incl - x;
    if (tid < bd) {
      const int base_row = b * bd;
      if (base_row + tid < ndst) {
        roff[base_row + tid] = beg + excl;
        rend[base_row + tid] = beg + excl + x;
      }
      cnt[tid] = excl;  // scatter cursors
    }
  }
  __syncthreads();

  for (int i = tid; i < n; i += 1024) {
    const uint2 r = sbuf[i];
    const int p = atomicAdd(&cnt[r.x >> 24], 1);
    bin[beg + p] = r;
  }
}

// ---------------------------------------------------------------------------
// Merged CSR SpMM + fused ReLU. One wave per destination row; 2 features per
// lane (uint = 2 bf16), 2 edges per wave (half-wave = one edge). Per 2 edges:
// 1 LDS broadcast read + 1 global dword gather + 2 unpack + 2 fmaf per lane.
// Final: acc += shfl_xor(acc,32); lanes 0-31 write float2 (coalesced 256B).
// ---------------------------------------------------------------------------
__global__ __launch_bounds__(256) void spmm_both_kernel(
    const uint2* __restrict__ edges_u, const int* __restrict__ uoff,
    const int* __restrict__ uend, const unsigned short* __restrict__ xw_item,
    float* __restrict__ out_user,
    const uint2* __restrict__ edges_i, const int* __restrict__ ioff,
    const int* __restrict__ iend, const unsigned short* __restrict__ xw_user,
    float* __restrict__ out_item) {
  __shared__ uint2 sedge[4][64];  // 2 KB, one 512B slice per wave
  const int wid = threadIdx.x >> 6, lane = threadIdx.x & 63;
  const int half = lane >> 5;          // 0: even edge, 1: odd edge
  const int fp = (lane & 31) * 2;      // feature pair base (element index)
  int d = blockIdx.x * 4 + wid;

  const uint2* edges; const unsigned short* xw; float* out; int beg, end;
  if (d < N_USERS) {
    edges = edges_u; xw = xw_item; out = out_user;
    beg = uoff[d]; end = uend[d];
  } else {
    d -= N_USERS;
    if (d >= N_ITEMS) return;
    edges = edges_i; xw = xw_user; out = out_item;
    beg = ioff[d]; end = iend[d];
  }

  float ax = 0.f, ay = 0.f;  // features fp, fp+1

  for (int kb = beg; kb < end; kb += 64) {
    const int nbt = min(64, end - kb);
    if (lane < nbt) sedge[wid][lane] = edges[kb + lane];

    int j = 0;
    // 8 pairs (16 edges) in flight
    for (; j + 16 <= nbt; j += 16) {
      uint2 e[8];
      #pragma unroll
      for (int q = 0; q < 8; ++q) e[q] = sedge[wid][j + 2 * q + half];
      unsigned g[8];
      #pragma unroll
      for (int q = 0; q < 8; ++q)
        g[q] = *(const unsigned*)(xw + ((e[q].x & 0xFFFFC0u) + fp));
      #pragma unroll
      for (int q = 0; q < 8; ++q) {
        const float v = __uint_as_float(e[q].y);
        ax = fmaf(v, __uint_as_float(g[q] << 16), ax);
        ay = fmaf(v, __uint_as_float(g[q] & 0xFFFF0000u), ay);
      }
    }
    for (; j + 2 <= nbt; j += 2) {
      const uint2 e = sedge[wid][j + half];
      const unsigned g = *(const unsigned*)(xw + ((e.x & 0xFFFFC0u) + fp));
      const float v = __uint_as_float(e.y);
      ax = fmaf(v, __uint_as_float(g << 16), ax);
      ay = fmaf(v, __uint_as_float(g & 0xFFFF0000u), ay);
    }
    if (j < nbt) {  // one leftover edge: only the low half contributes
      const uint2 e = sedge[wid][j];
      const unsigned g = *(const unsigned*)(xw + ((e.x & 0xFFFFC0u) + fp));
      const float v = half ? 0.f : __uint_as_float(e.y);
      ax = fmaf(v, __uint_as_float(g << 16), ax);
      ay = fmaf(v, __uint_as_float(g & 0xFFFF0000u), ay);
    }
  }

  // combine the two half-wave partial sums
  ax += __shfl_xor(ax, 32);
  ay += __shfl_xor(ay, 32);
  if (half == 0) {
    float2 o;
    o.x = fmaxf(ax, 0.f);
    o.y = fmaxf(ay, 0.f);
    *(float2*)(out + (size_t)d * DIM + fp) = o;
  }
}

extern "C" void kernel_launch(void* const* d_in, const int* in_sizes, int n_in,
                              void* d_out, int out_size, void* d_ws, size_t ws_size,
                              hipStream_t stream) {
  const float* user_x      = (const float*)d_in[0];
  const float* item_x      = (const float*)d_in[1];
  const float* user_weight = (const float*)d_in[2];
  const float* item_weight = (const float*)d_in[3];
  const int*   ui_rows     = (const int*)d_in[4];
  const int*   ui_cols     = (const int*)d_in[5];
  const float* ui_vals     = (const float*)d_in[6];

  float* out_user = (float*)d_out;
  float* out_item = (float*)d_out + (size_t)N_USERS * DIM;

  // ---- workspace layout (fixed-capacity bucket regions, sorted in place) --
  unsigned short* xw_user = (unsigned short*)d_ws;               // 6.4M bf16
  unsigned short* xw_item = xw_user + (size_t)N_USERS * DIM;     // 3.2M bf16
  uint2* binA = (uint2*)(xw_item + (size_t)N_ITEMS * DIM);       // user buckets
  uint2* binB = binA + (size_t)NBU * CAP;                        // item buckets
  int*   urow_off = (int*)(binB + (size_t)NBI * CAP);            // N_USERS
  int*   urow_end = urow_off + N_USERS;                          // N_USERS
  int*   irow_off = urow_end + N_USERS;                          // N_ITEMS
  int*   irow_end = irow_off + N_ITEMS;                          // N_ITEMS
  int*   cur_u    = irow_end + N_ITEMS;                          // NBU
  int*   cur_i    = cur_u + NBU;                                 // NBI
  // total ~49.3 MB

  // 1. Merged dense projections (bf16 out) + cursor seed in block 0.
  gemm_both_kernel<<<GEMM_BLKS_U + GEMM_BLKS_I, 256, 0, stream>>>(
      user_x, user_weight, xw_user, item_x, item_weight, xw_item, cur_u, cur_i);

  // 2. Combined two-direction coarse binning into capacity regions.
  const int nblk = (NNZ_EDGES + TILE - 1) / TILE;
  binning2_kernel<<<nblk, 1024, 0, stream>>>(ui_rows, ui_cols, ui_vals,
                                             cur_u, cur_i, binA, binB, NNZ_EDGES);

  // 3. Merged fine sort, in place per bucket (race-free) -> row ranges.
  fine_sort_both_kernel<<<NBU + NBI, 1024, 0, stream>>>(
      binA, cur_u, urow_off, urow_end,
      binB, cur_i, irow_off, irow_end);

  // 4. Merged CSR SpMM + fused ReLU (2 features/lane, 2 edges/wave).
  spmm_both_kernel<<<(N_USERS + N_ITEMS + 3) / 4, 256, 0, stream>>>(
      binA, urow_off, urow_end, xw_item, out_user,
      binB, irow_off, irow_end, xw_user, out_item);
}

// Round 15
// 121.430 us; speedup vs baseline: 1.2037x; 1.2037x over previous
//
#include <hip/hip_runtime.h>
#include <hip/hip_bf16.h>

#define N_USERS 100000
#define N_ITEMS 50000
#define NNZ_EDGES 1600000
#define DIM 64

#define BSHIFT_U 8
#define BD_U 256                             // user dests per coarse bucket
#define BSHIFT_I 7
#define BD_I 128                             // item dests per coarse bucket
#define NBU ((N_USERS + BD_U - 1) / BD_U)    // 391
#define NBI ((N_ITEMS + BD_I - 1) / BD_I)    // 391
#define NB_MAX 391
#define TILE 4096                            // edges per binning tile (4/thread @1024)
#define CAP 4608                             // bucket capacity (mean 4096 + 8 sigma)
#define GEMM_BLKS_U ((N_USERS + 63) / 64)    // 1563
#define GEMM_BLKS_I ((N_ITEMS + 63) / 64)    // 782

// Record layout: pk = (dst_local << 24) | (src << 6). Gather element index
// for feature f = (pk & 0xFFFFC0) + f.

__device__ inline unsigned short f32_to_bf16(float f) {
  unsigned u = __float_as_uint(f);
  unsigned r = (u + 0x7FFFu + ((u >> 16) & 1u)) >> 16;  // RNE
  return (unsigned short)r;
}
__device__ inline float bf16_to_f32(unsigned short h) {
  return __uint_as_float((unsigned)h << 16);
}

// ---------------------------------------------------------------------------
// Merged dense GEMM (both projections). Block 0 also seeds bucket cursors.
// ---------------------------------------------------------------------------
__global__ __launch_bounds__(256) void gemm_both_kernel(
    const float* __restrict__ Xu, const float* __restrict__ Wu,
    unsigned short* __restrict__ Yu,
    const float* __restrict__ Xi, const float* __restrict__ Wi,
    unsigned short* __restrict__ Yi,
    int* __restrict__ cur_u, int* __restrict__ cur_i) {
  __shared__ float sXT[64][64];   // [k][row]
  __shared__ float sW[64][64];    // [k][col]
  const int tid = threadIdx.x;

  if (blockIdx.x == 0) {
    for (int t = tid; t < NBU; t += 256) cur_u[t] = t * CAP;
    for (int t = tid; t < NBI; t += 256) cur_i[t] = t * CAP;
  }

  const float* X; const float* W; unsigned short* Y; int nrows, row_base;
  if (blockIdx.x < GEMM_BLKS_U) {
    X = Xu; W = Wu; Y = Yu; nrows = N_USERS; row_base = blockIdx.x * 64;
  } else {
    X = Xi; W = Wi; Y = Yi; nrows = N_ITEMS; row_base = (blockIdx.x - GEMM_BLKS_U) * 64;
  }

  {
    const float4* Wv = (const float4*)W;
    float4* sWv = (float4*)&sW[0][0];
    #pragma unroll
    for (int i = 0; i < 4; ++i) sWv[tid + i * 256] = Wv[tid + i * 256];
  }
  {
    const int r = tid & 63;
    const int k0 = (tid >> 6) * 16;
    const int grow = row_base + r;
    #pragma unroll
    for (int i = 0; i < 4; ++i) {
      float4 v = make_float4(0.f, 0.f, 0.f, 0.f);
      if (grow < nrows) v = ((const float4*)(X + (size_t)grow * DIM + k0))[i];
      sXT[k0 + i * 4 + 0][r] = v.x;
      sXT[k0 + i * 4 + 1][r] = v.y;
      sXT[k0 + i * 4 + 2][r] = v.z;
      sXT[k0 + i * 4 + 3][r] = v.w;
    }
  }
  __syncthreads();

  const int tx = tid & 15;
  const int ty = tid >> 4;
  float acc[4][4] = {{0.f}};

  #pragma unroll 8
  for (int k = 0; k < 64; ++k) {
    const float4 a = *(const float4*)&sXT[k][ty * 4];
    const float4 b = *(const float4*)&sW[k][tx * 4];
    acc[0][0] = fmaf(a.x, b.x, acc[0][0]);
    acc[0][1] = fmaf(a.x, b.y, acc[0][1]);
    acc[0][2] = fmaf(a.x, b.z, acc[0][2]);
    acc[0][3] = fmaf(a.x, b.w, acc[0][3]);
    acc[1][0] = fmaf(a.y, b.x, acc[1][0]);
    acc[1][1] = fmaf(a.y, b.y, acc[1][1]);
    acc[1][2] = fmaf(a.y, b.z, acc[1][2]);
    acc[1][3] = fmaf(a.y, b.w, acc[1][3]);
    acc[2][0] = fmaf(a.z, b.x, acc[2][0]);
    acc[2][1] = fmaf(a.z, b.y, acc[2][1]);
    acc[2][2] = fmaf(a.z, b.z, acc[2][2]);
    acc[2][3] = fmaf(a.z, b.w, acc[2][3]);
    acc[3][0] = fmaf(a.w, b.x, acc[3][0]);
    acc[3][1] = fmaf(a.w, b.y, acc[3][1]);
    acc[3][2] = fmaf(a.w, b.z, acc[3][2]);
    acc[3][3] = fmaf(a.w, b.w, acc[3][3]);
  }

  #pragma unroll
  for (int r = 0; r < 4; ++r) {
    const int grow = row_base + ty * 4 + r;
    if (grow < nrows) {
      ushort4 o;
      o.x = f32_to_bf16(acc[r][0]);
      o.y = f32_to_bf16(acc[r][1]);
      o.z = f32_to_bf16(acc[r][2]);
      o.w = f32_to_bf16(acc[r][3]);
      *(ushort4*)(Y + (size_t)grow * DIM + tx * 4) = o;
    }
  }
}

// ---------------------------------------------------------------------------
// Combined two-direction LDS-binning, 1024 threads (4 records/thread).
// Writes into fixed-capacity per-bucket regions (cursor base = b*CAP).
// ---------------------------------------------------------------------------
__global__ __launch_bounds__(1024) void binning2_kernel(
    const int* __restrict__ rows, const int* __restrict__ cols,
    const float* __restrict__ vals,
    int* __restrict__ cur_u, int* __restrict__ cur_i,
    uint2* __restrict__ out_u, uint2* __restrict__ out_i, int nnz) {
  __shared__ int sh[NB_MAX];          // hist -> excl -> cursor -> global base
  __shared__ int scnt[NB_MAX];        // counts -> excl
  __shared__ uint2 sbuf[TILE];        // 32 KB
  __shared__ unsigned short sbk[TILE];// 8 KB
  __shared__ int s_w[16];

  const int tid = threadIdx.x, lane = tid & 63, wid = tid >> 6;
  const int tbase = blockIdx.x * TILE;
  const int total = min(TILE, nnz - tbase);

  int er[4], ec[4]; unsigned ev[4];
  #pragma unroll
  for (int k = 0; k < 4; ++k) {
    const int i = tbase + k * 1024 + tid;
    if (i < nnz) {
      er[k] = rows[i];
      ec[k] = cols[i];
      ev[k] = __float_as_uint(vals[i]);
    } else {
      er[k] = -1; ec[k] = 0; ev[k] = 0;
    }
  }

#define BIN_PHASE(BKEXPR, PKEXPR, NB, CUR, OUT)                                \
  {                                                                            \
    for (int j = tid; j < (NB); j += 1024) sh[j] = 0;                          \
    __syncthreads();                                                           \
    int bk[4]; unsigned pk[4];                                                 \
    _Pragma("unroll")                                                          \
    for (int k = 0; k < 4; ++k) {                                              \
      if (er[k] >= 0) {                                                        \
        bk[k] = (BKEXPR); pk[k] = (PKEXPR);                                    \
        atomicAdd(&sh[bk[k]], 1);                                              \
      } else { bk[k] = -1; pk[k] = 0; }                                        \
    }                                                                          \
    __syncthreads();                                                           \
    {                                                                          \
      const int x = (tid < (NB)) ? sh[tid] : 0;                                \
      int incl = x;                                                            \
      _Pragma("unroll")                                                        \
      for (int d = 1; d < 64; d <<= 1) {                                       \
        int t = __shfl_up(incl, d);                                            \
        if (lane >= d) incl += t;                                              \
      }                                                                        \
      if (lane == 63) s_w[wid] = incl;                                         \
      __syncthreads();                                                         \
      if (tid == 0) {                                                          \
        int a = 0;                                                             \
        _Pragma("unroll")                                                      \
        for (int w = 0; w < 16; ++w) { const int t = s_w[w]; s_w[w] = a; a += t; } \
      }                                                                        \
      __syncthreads();                                                         \
      const int excl = s_w[wid] + incl - x;                                    \
      if (tid < (NB)) { scnt[tid] = x; sh[tid] = excl; }                       \
      __syncthreads();                                                         \
    }                                                                          \
    _Pragma("unroll")                                                          \
    for (int k = 0; k < 4; ++k) {                                              \
      if (bk[k] >= 0) {                                                        \
        const int p = atomicAdd(&sh[bk[k]], 1);                                \
        sbuf[p] = make_uint2(pk[k], ev[k]);                                    \
        sbk[p] = (unsigned short)bk[k];                                        \
      }                                                                        \
    }                                                                          \
    __syncthreads();                                                           \
    if (tid < (NB)) {                                                          \
      const int c = scnt[tid];                                                 \
      const int excl = sh[tid] - c;                                            \
      int g = 0;                                                               \
      if (c > 0) g = atomicAdd(&(CUR)[tid], c);                                \
      scnt[tid] = excl;                                                        \
      sh[tid] = g;                                                             \
    }                                                                          \
    __syncthreads();                                                           \
    for (int p = tid; p < total; p += 1024) {                                  \
      const int b = sbk[p];                                                    \
      (OUT)[sh[b] + (p - scnt[b])] = sbuf[p];                                  \
    }                                                                          \
    __syncthreads();                                                           \
  }

  BIN_PHASE(er[k] >> BSHIFT_U,
            ((unsigned)(er[k] & (BD_U - 1)) << 24) | ((unsigned)ec[k] << 6),
            NBU, cur_u, out_u)
  BIN_PHASE(ec[k] >> BSHIFT_I,
            ((unsigned)(ec[k] & (BD_I - 1)) << 24) | ((unsigned)er[k] << 6),
            NBI, cur_i, out_i)
#undef BIN_PHASE
}

// ---------------------------------------------------------------------------
// Fused fine-sort + SpMM + ReLU. One 1024-thread block (16 waves) per coarse
// bucket. Records staged to REGISTERS (5 uint2/thread) + LDS hist -> scan ->
// scatter into ONE 36.9KB LDS buffer (sorted). Then wave w processes rows
// w, w+16, ... reading edges from LDS (uniform-address broadcast) with the
// r13-proven gather loop (lane = feature, ushort gather, ILP-8).
// ---------------------------------------------------------------------------
__global__ __launch_bounds__(1024) void sort_spmm_kernel(
    const uint2* __restrict__ bin_u, const int* __restrict__ cur_u,
    const unsigned short* __restrict__ xw_item, float* __restrict__ out_user,
    const uint2* __restrict__ bin_i, const int* __restrict__ cur_i,
    const unsigned short* __restrict__ xw_user, float* __restrict__ out_item) {
  __shared__ uint2 sbuf[CAP];     // 36.9 KB (sorted records)
  __shared__ int cnt[256];        // hist -> scatter cursor -> row end
  __shared__ int roff[256];       // row start
  __shared__ int s_w[4];
  const int tid = threadIdx.x;
  const int lane = tid & 63, wid = tid >> 6;

  const uint2* bin; const int* cur; const unsigned short* xw; float* out;
  int b, bd, ndst;
  if (blockIdx.x < NBU) {
    b = blockIdx.x; bd = BD_U; ndst = N_USERS;
    bin = bin_u; cur = cur_u; xw = xw_item; out = out_user;
  } else {
    b = blockIdx.x - NBU; bd = BD_I; ndst = N_ITEMS;
    bin = bin_i; cur = cur_i; xw = xw_user; out = out_item;
  }
  const int beg = b * CAP;
  const int n = min(cur[b] - beg, CAP);

  if (tid < bd) cnt[tid] = 0;
  __syncthreads();

  // Stage records in registers + LDS histogram of local dests.
  uint2 rg[5];
  #pragma unroll
  for (int k = 0; k < 5; ++k) {
    const int i = k * 1024 + tid;
    if (i < n) {
      rg[k] = bin[beg + i];
      atomicAdd(&cnt[rg[k].x >> 24], 1);
    } else {
      rg[k] = make_uint2(0u, 0u);
    }
  }
  __syncthreads();

  // Exclusive scan of cnt[0..bd) in the first 256 threads (bd <= 256).
  int x = 0, incl = 0;
  if (tid < 256) {
    x = (tid < bd) ? cnt[tid] : 0;
    incl = x;
    #pragma unroll
    for (int d = 1; d < 64; d <<= 1) {
      int t = __shfl_up(incl, d);
      if (lane >= d) incl += t;
    }
    if (lane == 63) s_w[wid] = incl;
  }
  __syncthreads();
  if (tid == 0) {
    int a = 0;
    #pragma unroll
    for (int w = 0; w < 4; ++w) { const int t = s_w[w]; s_w[w] = a; a += t; }
  }
  __syncthreads();
  if (tid < 256) {
    const int excl = s_w[wid] + incl - x;
    if (tid < bd) {
      roff[tid] = excl;   // row start
      cnt[tid] = excl;    // scatter cursor (becomes row end after scatter)
    }
  }
  __syncthreads();

  // Scatter registers -> sorted LDS buffer.
  #pragma unroll
  for (int k = 0; k < 5; ++k) {
    const int i = k * 1024 + tid;
    if (i < n) {
      const int p = atomicAdd(&cnt[rg[k].x >> 24], 1);
      sbuf[p] = rg[k];
    }
  }
  __syncthreads();

  // SpMM: wave w handles rows w, w+16, ... ; lane = feature.
  const unsigned short* __restrict__ xwl = xw + lane;
  for (int r = wid; r < bd; r += 16) {
    const int rb = roff[r], re = cnt[r];
    float acc = 0.f;
    int j = rb;
    for (; j + 8 <= re; j += 8) {
      uint2 e[8];
      #pragma unroll
      for (int q = 0; q < 8; ++q) e[q] = sbuf[j + q];   // LDS broadcast
      unsigned short h[8];
      #pragma unroll
      for (int q = 0; q < 8; ++q) h[q] = xwl[e[q].x & 0xFFFFC0u];
      #pragma unroll
      for (int q = 0; q < 8; ++q)
        acc = fmaf(__uint_as_float(e[q].y), bf16_to_f32(h[q]), acc);
    }
    for (; j + 4 <= re; j += 4) {
      uint2 e[4];
      #pragma unroll
      for (int q = 0; q < 4; ++q) e[q] = sbuf[j + q];
      unsigned short h[4];
      #pragma unroll
      for (int q = 0; q < 4; ++q) h[q] = xwl[e[q].x & 0xFFFFC0u];
      #pragma unroll
      for (int q = 0; q < 4; ++q)
        acc = fmaf(__uint_as_float(e[q].y), bf16_to_f32(h[q]), acc);
    }
    for (; j < re; ++j) {
      const uint2 e = sbuf[j];
      acc = fmaf(__uint_as_float(e.y), bf16_to_f32(xwl[e.x & 0xFFFFC0u]), acc);
    }
    const int grow = b * bd + r;
    if (grow < ndst) out[(size_t)grow * DIM + lane] = fmaxf(acc, 0.f);
  }
}

extern "C" void kernel_launch(void* const* d_in, const int* in_sizes, int n_in,
                              void* d_out, int out_size, void* d_ws, size_t ws_size,
                              hipStream_t stream) {
  const float* user_x      = (const float*)d_in[0];
  const float* item_x      = (const float*)d_in[1];
  const float* user_weight = (const float*)d_in[2];
  const float* item_weight = (const float*)d_in[3];
  const int*   ui_rows     = (const int*)d_in[4];
  const int*   ui_cols     = (const int*)d_in[5];
  const float* ui_vals     = (const float*)d_in[6];

  float* out_user = (float*)d_out;
  float* out_item = (float*)d_out + (size_t)N_USERS * DIM;

  // ---- workspace layout (fixed-capacity bucket regions) ------------------
  unsigned short* xw_user = (unsigned short*)d_ws;               // 6.4M bf16
  unsigned short* xw_item = xw_user + (size_t)N_USERS * DIM;     // 3.2M bf16
  uint2* binA = (uint2*)(xw_item + (size_t)N_ITEMS * DIM);       // user buckets
  uint2* binB = binA + (size_t)NBU * CAP;                        // item buckets
  int*   cur_u = (int*)(binB + (size_t)NBI * CAP);               // NBU
  int*   cur_i = cur_u + NBU;                                    // NBI
  // total ~48.1 MB

  // 1. Merged dense projections (bf16 out) + cursor seed in block 0.
  gemm_both_kernel<<<GEMM_BLKS_U + GEMM_BLKS_I, 256, 0, stream>>>(
      user_x, user_weight, xw_user, item_x, item_weight, xw_item, cur_u, cur_i);

  // 2. Combined two-direction coarse binning into capacity regions.
  const int nblk = (NNZ_EDGES + TILE - 1) / TILE;
  binning2_kernel<<<nblk, 1024, 0, stream>>>(ui_rows, ui_cols, ui_vals,
                                             cur_u, cur_i, binA, binB, NNZ_EDGES);

  // 3. Fused fine-sort + SpMM + ReLU (one block per coarse bucket).
  sort_spmm_kernel<<<NBU + NBI, 1024, 0, stream>>>(
      binA, cur_u, xw_item, out_user,
      binB, cur_i, xw_user, out_item);
}

// Round 16
// 117.494 us; speedup vs baseline: 1.2440x; 1.0335x over previous
//
#include <hip/hip_runtime.h>
#include <hip/hip_bf16.h>

#define N_USERS 100000
#define N_ITEMS 50000
#define NNZ_EDGES 1600000
#define DIM 64

#define BSHIFT_U 7
#define BD_U 128                             // user dests per coarse bucket
#define BSHIFT_I 6
#define BD_I 64                              // item dests per coarse bucket
#define NBU ((N_USERS + BD_U - 1) / BD_U)    // 782
#define NBI ((N_ITEMS + BD_I - 1) / BD_I)    // 782
#define NB_MAX 782
#define TILE 4096                            // edges per binning tile (4/thread @1024)
#define CAP 2432                             // bucket capacity (mean 2048 + 8.5 sigma)
#define GEMM_BLKS_U ((N_USERS + 63) / 64)    // 1563
#define GEMM_BLKS_I ((N_ITEMS + 63) / 64)    // 782

// Record layout: pk = (dst_local << 24) | (src << 6). Gather element index
// for feature f = (pk & 0xFFFFC0) + f.

__device__ inline unsigned short f32_to_bf16(float f) {
  unsigned u = __float_as_uint(f);
  unsigned r = (u + 0x7FFFu + ((u >> 16) & 1u)) >> 16;  // RNE
  return (unsigned short)r;
}
__device__ inline float bf16_to_f32(unsigned short h) {
  return __uint_as_float((unsigned)h << 16);
}

// ---------------------------------------------------------------------------
// Merged dense GEMM (both projections). Block 0 also seeds bucket cursors.
// ---------------------------------------------------------------------------
__global__ __launch_bounds__(256) void gemm_both_kernel(
    const float* __restrict__ Xu, const float* __restrict__ Wu,
    unsigned short* __restrict__ Yu,
    const float* __restrict__ Xi, const float* __restrict__ Wi,
    unsigned short* __restrict__ Yi,
    int* __restrict__ cur_u, int* __restrict__ cur_i) {
  __shared__ float sXT[64][64];   // [k][row]
  __shared__ float sW[64][64];    // [k][col]
  const int tid = threadIdx.x;

  if (blockIdx.x == 0) {
    for (int t = tid; t < NBU; t += 256) cur_u[t] = t * CAP;
    for (int t = tid; t < NBI; t += 256) cur_i[t] = t * CAP;
  }

  const float* X; const float* W; unsigned short* Y; int nrows, row_base;
  if (blockIdx.x < GEMM_BLKS_U) {
    X = Xu; W = Wu; Y = Yu; nrows = N_USERS; row_base = blockIdx.x * 64;
  } else {
    X = Xi; W = Wi; Y = Yi; nrows = N_ITEMS; row_base = (blockIdx.x - GEMM_BLKS_U) * 64;
  }

  {
    const float4* Wv = (const float4*)W;
    float4* sWv = (float4*)&sW[0][0];
    #pragma unroll
    for (int i = 0; i < 4; ++i) sWv[tid + i * 256] = Wv[tid + i * 256];
  }
  {
    const int r = tid & 63;
    const int k0 = (tid >> 6) * 16;
    const int grow = row_base + r;
    #pragma unroll
    for (int i = 0; i < 4; ++i) {
      float4 v = make_float4(0.f, 0.f, 0.f, 0.f);
      if (grow < nrows) v = ((const float4*)(X + (size_t)grow * DIM + k0))[i];
      sXT[k0 + i * 4 + 0][r] = v.x;
      sXT[k0 + i * 4 + 1][r] = v.y;
      sXT[k0 + i * 4 + 2][r] = v.z;
      sXT[k0 + i * 4 + 3][r] = v.w;
    }
  }
  __syncthreads();

  const int tx = tid & 15;
  const int ty = tid >> 4;
  float acc[4][4] = {{0.f}};

  #pragma unroll 8
  for (int k = 0; k < 64; ++k) {
    const float4 a = *(const float4*)&sXT[k][ty * 4];
    const float4 b = *(const float4*)&sW[k][tx * 4];
    acc[0][0] = fmaf(a.x, b.x, acc[0][0]);
    acc[0][1] = fmaf(a.x, b.y, acc[0][1]);
    acc[0][2] = fmaf(a.x, b.z, acc[0][2]);
    acc[0][3] = fmaf(a.x, b.w, acc[0][3]);
    acc[1][0] = fmaf(a.y, b.x, acc[1][0]);
    acc[1][1] = fmaf(a.y, b.y, acc[1][1]);
    acc[1][2] = fmaf(a.y, b.z, acc[1][2]);
    acc[1][3] = fmaf(a.y, b.w, acc[1][3]);
    acc[2][0] = fmaf(a.z, b.x, acc[2][0]);
    acc[2][1] = fmaf(a.z, b.y, acc[2][1]);
    acc[2][2] = fmaf(a.z, b.z, acc[2][2]);
    acc[2][3] = fmaf(a.z, b.w, acc[2][3]);
    acc[3][0] = fmaf(a.w, b.x, acc[3][0]);
    acc[3][1] = fmaf(a.w, b.y, acc[3][1]);
    acc[3][2] = fmaf(a.w, b.z, acc[3][2]);
    acc[3][3] = fmaf(a.w, b.w, acc[3][3]);
  }

  #pragma unroll
  for (int r = 0; r < 4; ++r) {
    const int grow = row_base + ty * 4 + r;
    if (grow < nrows) {
      ushort4 o;
      o.x = f32_to_bf16(acc[r][0]);
      o.y = f32_to_bf16(acc[r][1]);
      o.z = f32_to_bf16(acc[r][2]);
      o.w = f32_to_bf16(acc[r][3]);
      *(ushort4*)(Y + (size_t)grow * DIM + tx * 4) = o;
    }
  }
}

// ---------------------------------------------------------------------------
// Combined two-direction LDS-binning, 1024 threads (4 records/thread).
// Writes into fixed-capacity per-bucket regions (cursor base = b*CAP).
// ---------------------------------------------------------------------------
__global__ __launch_bounds__(1024) void binning2_kernel(
    const int* __restrict__ rows, const int* __restrict__ cols,
    const float* __restrict__ vals,
    int* __restrict__ cur_u, int* __restrict__ cur_i,
    uint2* __restrict__ out_u, uint2* __restrict__ out_i, int nnz) {
  __shared__ int sh[NB_MAX];          // hist -> excl -> cursor -> global base
  __shared__ int scnt[NB_MAX];        // counts -> excl
  __shared__ uint2 sbuf[TILE];        // 32 KB
  __shared__ unsigned short sbk[TILE];// 8 KB
  __shared__ int s_w[16];

  const int tid = threadIdx.x, lane = tid & 63, wid = tid >> 6;
  const int tbase = blockIdx.x * TILE;
  const int total = min(TILE, nnz - tbase);

  int er[4], ec[4]; unsigned ev[4];
  #pragma unroll
  for (int k = 0; k < 4; ++k) {
    const int i = tbase + k * 1024 + tid;
    if (i < nnz) {
      er[k] = rows[i];
      ec[k] = cols[i];
      ev[k] = __float_as_uint(vals[i]);
    } else {
      er[k] = -1; ec[k] = 0; ev[k] = 0;
    }
  }

#define BIN_PHASE(BKEXPR, PKEXPR, NB, CUR, OUT)                                \
  {                                                                            \
    for (int j = tid; j < (NB); j += 1024) sh[j] = 0;                          \
    __syncthreads();                                                           \
    int bk[4]; unsigned pk[4];                                                 \
    _Pragma("unroll")                                                          \
    for (int k = 0; k < 4; ++k) {                                              \
      if (er[k] >= 0) {                                                        \
        bk[k] = (BKEXPR); pk[k] = (PKEXPR);                                    \
        atomicAdd(&sh[bk[k]], 1);                                              \
      } else { bk[k] = -1; pk[k] = 0; }                                        \
    }                                                                          \
    __syncthreads();                                                           \
    {                                                                          \
      const int x = (tid < (NB)) ? sh[tid] : 0;                                \
      int incl = x;                                                            \
      _Pragma("unroll")                                                        \
      for (int d = 1; d < 64; d <<= 1) {                                       \
        int t = __shfl_up(incl, d);                                            \
        if (lane >= d) incl += t;                                              \
      }                                                                        \
      if (lane == 63) s_w[wid] = incl;                                         \
      __syncthreads();                                                         \
      if (tid == 0) {                                                          \
        int a = 0;                                                             \
        _Pragma("unroll")                                                      \
        for (int w = 0; w < 16; ++w) { const int t = s_w[w]; s_w[w] = a; a += t; } \
      }                                                                        \
      __syncthreads();                                                         \
      const int excl = s_w[wid] + incl - x;                                    \
      if (tid < (NB)) { scnt[tid] = x; sh[tid] = excl; }                       \
      __syncthreads();                                                         \
    }                                                                          \
    _Pragma("unroll")                                                          \
    for (int k = 0; k < 4; ++k) {                                              \
      if (bk[k] >= 0) {                                                        \
        const int p = atomicAdd(&sh[bk[k]], 1);                                \
        sbuf[p] = make_uint2(pk[k], ev[k]);                                    \
        sbk[p] = (unsigned short)bk[k];                                        \
      }                                                                        \
    }                                                                          \
    __syncthreads();                                                           \
    if (tid < (NB)) {                                                          \
      const int c = scnt[tid];                                                 \
      const int excl = sh[tid] - c;                                            \
      int g = 0;                                                               \
      if (c > 0) g = atomicAdd(&(CUR)[tid], c);                                \
      scnt[tid] = excl;                                                        \
      sh[tid] = g;                                                             \
    }                                                                          \
    __syncthreads();                                                           \
    for (int p = tid; p < total; p += 1024) {                                  \
      const int b = sbk[p];                                                    \
      (OUT)[sh[b] + (p - scnt[b])] = sbuf[p];                                  \
    }                                                                          \
    __syncthreads();                                                           \
  }

  BIN_PHASE(er[k] >> BSHIFT_U,
            ((unsigned)(er[k] & (BD_U - 1)) << 24) | ((unsigned)ec[k] << 6),
            NBU, cur_u, out_u)
  BIN_PHASE(ec[k] >> BSHIFT_I,
            ((unsigned)(ec[k] & (BD_I - 1)) << 24) | ((unsigned)er[k] << 6),
            NBI, cur_i, out_i)
#undef BIN_PHASE
}

// ---------------------------------------------------------------------------
// Fused fine-sort + SpMM + ReLU. One 512-thread block (8 waves) per coarse
// bucket (1564 blocks, ~20.5KB LDS -> 4 blocks/CU). Records staged to
// registers (5 uint2/thread) + LDS hist -> scan -> scatter into one sorted
// LDS buffer. Wave w processes rows w, w+8, ...; lane = feature; ILP-16
// independent bf16 gathers in flight.
// ---------------------------------------------------------------------------
__global__ __launch_bounds__(512) void sort_spmm_kernel(
    const uint2* __restrict__ bin_u, const int* __restrict__ cur_u,
    const unsigned short* __restrict__ xw_item, float* __restrict__ out_user,
    const uint2* __restrict__ bin_i, const int* __restrict__ cur_i,
    const unsigned short* __restrict__ xw_user, float* __restrict__ out_item) {
  __shared__ uint2 sbuf[CAP];     // 19.5 KB (sorted records)
  __shared__ int cnt[128];        // hist -> scatter cursor -> row end
  __shared__ int roff[128];       // row start
  __shared__ int s_w[2];
  const int tid = threadIdx.x;
  const int lane = tid & 63, wid = tid >> 6;

  const uint2* bin; const int* cur; const unsigned short* xw; float* out;
  int b, bd, ndst;
  if (blockIdx.x < NBU) {
    b = blockIdx.x; bd = BD_U; ndst = N_USERS;
    bin = bin_u; cur = cur_u; xw = xw_item; out = out_user;
  } else {
    b = blockIdx.x - NBU; bd = BD_I; ndst = N_ITEMS;
    bin = bin_i; cur = cur_i; xw = xw_user; out = out_item;
  }
  const int beg = b * CAP;
  const int n = min(cur[b] - beg, CAP);

  if (tid < bd) cnt[tid] = 0;
  __syncthreads();

  // Stage records in registers + LDS histogram of local dests.
  uint2 rg[5];
  #pragma unroll
  for (int k = 0; k < 5; ++k) {
    const int i = k * 512 + tid;
    if (i < n) {
      rg[k] = bin[beg + i];
      atomicAdd(&cnt[rg[k].x >> 24], 1);
    } else {
      rg[k] = make_uint2(0u, 0u);
    }
  }
  __syncthreads();

  // Exclusive scan of cnt[0..bd) in the first 128 threads (bd <= 128).
  int x = 0, incl = 0;
  if (tid < 128) {
    x = (tid < bd) ? cnt[tid] : 0;
    incl = x;
    #pragma unroll
    for (int d = 1; d < 64; d <<= 1) {
      int t = __shfl_up(incl, d);
      if (lane >= d) incl += t;
    }
    if (lane == 63) s_w[wid] = incl;
  }
  __syncthreads();
  if (tid == 0) {
    const int t0 = s_w[0];
    s_w[0] = 0;
    s_w[1] = t0;
  }
  __syncthreads();
  if (tid < 128) {
    const int excl = s_w[wid] + incl - x;
    if (tid < bd) {
      roff[tid] = excl;   // row start
      cnt[tid] = excl;    // scatter cursor (becomes row end after scatter)
    }
  }
  __syncthreads();

  // Scatter registers -> sorted LDS buffer.
  #pragma unroll
  for (int k = 0; k < 5; ++k) {
    const int i = k * 512 + tid;
    if (i < n) {
      const int p = atomicAdd(&cnt[rg[k].x >> 24], 1);
      sbuf[p] = rg[k];
    }
  }
  __syncthreads();

  // SpMM: wave w handles rows w, w+8, ... ; lane = feature.
  const unsigned short* __restrict__ xwl = xw + lane;
  for (int r = wid; r < bd; r += 8) {
    const int rb = roff[r], re = cnt[r];
    float acc = 0.f;
    int j = rb;
    for (; j + 16 <= re; j += 16) {
      uint2 e[16];
      #pragma unroll
      for (int q = 0; q < 16; ++q) e[q] = sbuf[j + q];   // LDS broadcast
      unsigned short h[16];
      #pragma unroll
      for (int q = 0; q < 16; ++q) h[q] = xwl[e[q].x & 0xFFFFC0u];
      #pragma unroll
      for (int q = 0; q < 16; ++q)
        acc = fmaf(__uint_as_float(e[q].y), bf16_to_f32(h[q]), acc);
    }
    for (; j + 8 <= re; j += 8) {
      uint2 e[8];
      #pragma unroll
      for (int q = 0; q < 8; ++q) e[q] = sbuf[j + q];
      unsigned short h[8];
      #pragma unroll
      for (int q = 0; q < 8; ++q) h[q] = xwl[e[q].x & 0xFFFFC0u];
      #pragma unroll
      for (int q = 0; q < 8; ++q)
        acc = fmaf(__uint_as_float(e[q].y), bf16_to_f32(h[q]), acc);
    }
    for (; j + 4 <= re; j += 4) {
      uint2 e[4];
      #pragma unroll
      for (int q = 0; q < 4; ++q) e[q] = sbuf[j + q];
      unsigned short h[4];
      #pragma unroll
      for (int q = 0; q < 4; ++q) h[q] = xwl[e[q].x & 0xFFFFC0u];
      #pragma unroll
      for (int q = 0; q < 4; ++q)
        acc = fmaf(__uint_as_float(e[q].y), bf16_to_f32(h[q]), acc);
    }
    for (; j < re; ++j) {
      const uint2 e = sbuf[j];
      acc = fmaf(__uint_as_float(e.y), bf16_to_f32(xwl[e.x & 0xFFFFC0u]), acc);
    }
    const int grow = b * bd + r;
    if (grow < ndst) out[(size_t)grow * DIM + lane] = fmaxf(acc, 0.f);
  }
}

extern "C" void kernel_launch(void* const* d_in, const int* in_sizes, int n_in,
                              void* d_out, int out_size, void* d_ws, size_t ws_size,
                              hipStream_t stream) {
  const float* user_x      = (const float*)d_in[0];
  const float* item_x      = (const float*)d_in[1];
  const float* user_weight = (const float*)d_in[2];
  const float* item_weight = (const float*)d_in[3];
  const int*   ui_rows     = (const int*)d_in[4];
  const int*   ui_cols     = (const int*)d_in[5];
  const float* ui_vals     = (const float*)d_in[6];

  float* out_user = (float*)d_out;
  float* out_item = (float*)d_out + (size_t)N_USERS * DIM;

  // ---- workspace layout (fixed-capacity bucket regions) ------------------
  unsigned short* xw_user = (unsigned short*)d_ws;               // 6.4M bf16
  unsigned short* xw_item = xw_user + (size_t)N_USERS * DIM;     // 3.2M bf16
  uint2* binA = (uint2*)(xw_item + (size_t)N_ITEMS * DIM);       // user buckets
  uint2* binB = binA + (size_t)NBU * CAP;                        // item buckets
  int*   cur_u = (int*)(binB + (size_t)NBI * CAP);               // NBU
  int*   cur_i = cur_u + NBU;                                    // NBI
  // total ~49.7 MB

  // 1. Merged dense projections (bf16 out) + cursor seed in block 0.
  gemm_both_kernel<<<GEMM_BLKS_U + GEMM_BLKS_I, 256, 0, stream>>>(
      user_x, user_weight, xw_user, item_x, item_weight, xw_item, cur_u, cur_i);

  // 2. Combined two-direction coarse binning into capacity regions.
  const int nblk = (NNZ_EDGES + TILE - 1) / TILE;
  binning2_kernel<<<nblk, 1024, 0, stream>>>(ui_rows, ui_cols, ui_vals,
                                             cur_u, cur_i, binA, binB, NNZ_EDGES);

  // 3. Fused fine-sort + SpMM + ReLU (one 512-thread block per bucket).
  sort_spmm_kernel<<<NBU + NBI, 512, 0, stream>>>(
      binA, cur_u, xw_item, out_user,
      binB, cur_i, xw_user, out_item);
}

// Round 17
// 110.909 us; speedup vs baseline: 1.3179x; 1.0594x over previous
//
#include <hip/hip_runtime.h>
#include <hip/hip_bf16.h>

#define N_USERS 100000
#define N_ITEMS 50000
#define NNZ_EDGES 1600000
#define DIM 64

#define BSHIFT_U 7
#define BD_U 128                             // user dests per coarse bucket
#define BSHIFT_I 6
#define BD_I 64                              // item dests per coarse bucket
#define NBU ((N_USERS + BD_U - 1) / BD_U)    // 782
#define NBI ((N_ITEMS + BD_I - 1) / BD_I)    // 782
#define NB_MAX 782
#define TILE 4096                            // edges per binning tile (8/thread @512)
#define CAP 2432                             // bucket capacity (mean 2048 + 8.5 sigma)

// prep grid layout: [0, PREP_GU) user gemm, [PREP_GU, +PREP_GI) item gemm,
// [PREP_GU+PREP_GI, +PREP_BIN) binning.
#define PREP_GU ((N_USERS + 127) / 128)      // 782
#define PREP_GI ((N_ITEMS + 127) / 128)      // 391
#define PREP_BIN ((NNZ_EDGES + TILE - 1) / TILE) // 391

// Record layout: pk = (dst_local << 25) | (src_byte_off << 0) where
// src_byte_off = src * 128 (bf16 row = 128 B) lives in bits 7..24.
// Gather address for feature lane = (char*)xw + lane*2 + (pk & 0x01FFFF80).

__device__ inline unsigned short f32_to_bf16(float f) {
  unsigned u = __float_as_uint(f);
  unsigned r = (u + 0x7FFFu + ((u >> 16) & 1u)) >> 16;  // RNE
  return (unsigned short)r;
}
__device__ inline float bf16_to_f32(unsigned short h) {
  return __uint_as_float((unsigned)h << 16);
}

// ---------------------------------------------------------------------------
// PREP: merged dense GEMM + two-direction binning in ONE dispatch (they are
// independent; merging overlaps VALU-heavy gemm with memory-heavy binning).
// 512 threads. LDS is a manual union (48 KB -> 3 blocks/CU).
//   gemm path: 128 rows/block = 2 sub-tiles of 64 rows; W staged once.
//   binning path: 8 records/thread; offset-based cursors (memset 0).
// ---------------------------------------------------------------------------
__global__ __launch_bounds__(512) void prep_kernel(
    const float* __restrict__ Xu, const float* __restrict__ Wu,
    unsigned short* __restrict__ Yu,
    const float* __restrict__ Xi, const float* __restrict__ Wi,
    unsigned short* __restrict__ Yi,
    const int* __restrict__ rows, const int* __restrict__ cols,
    const float* __restrict__ vals,
    int* __restrict__ cur_u, int* __restrict__ cur_i,
    uint2* __restrict__ out_u, uint2* __restrict__ out_i) {
  __shared__ char smem[49152];
  const int tid = threadIdx.x, lane = tid & 63, wid = tid >> 6;

  if (blockIdx.x < PREP_GU + PREP_GI) {
    // ------------------------- GEMM path ---------------------------------
    float* sW = (float*)smem;                       // [64][64] 16 KB
    float* sXTb = (float*)(smem + 16384);           // [2][64][64] 32 KB
    const int sub = tid >> 8;                       // 0/1
    const int stid = tid & 255;

    const float* X; const float* W; unsigned short* Y; int nrows, row_base;
    if (blockIdx.x < PREP_GU) {
      X = Xu; W = Wu; Y = Yu; nrows = N_USERS;
      row_base = blockIdx.x * 128 + sub * 64;
    } else {
      X = Xi; W = Wi; Y = Yi; nrows = N_ITEMS;
      row_base = (blockIdx.x - PREP_GU) * 128 + sub * 64;
    }

    {
      const float4* Wv = (const float4*)W;
      float4* sWv = (float4*)sW;
      #pragma unroll
      for (int i = 0; i < 2; ++i) sWv[tid + i * 512] = Wv[tid + i * 512];
    }
    float* sXT = sXTb + sub * 64 * 64;              // [k][row]
    {
      const int r = stid & 63;
      const int k0 = (stid >> 6) * 16;
      const int grow = row_base + r;
      #pragma unroll
      for (int i = 0; i < 4; ++i) {
        float4 v = make_float4(0.f, 0.f, 0.f, 0.f);
        if (grow < nrows) v = ((const float4*)(X + (size_t)grow * DIM + k0))[i];
        sXT[(k0 + i * 4 + 0) * 64 + r] = v.x;
        sXT[(k0 + i * 4 + 1) * 64 + r] = v.y;
        sXT[(k0 + i * 4 + 2) * 64 + r] = v.z;
        sXT[(k0 + i * 4 + 3) * 64 + r] = v.w;
      }
    }
    __syncthreads();

    const int tx = stid & 15;
    const int ty = stid >> 4;
    float acc[4][4] = {{0.f}};

    #pragma unroll 8
    for (int k = 0; k < 64; ++k) {
      const float4 a = *(const float4*)&sXT[k * 64 + ty * 4];
      const float4 b = *(const float4*)&sW[k * 64 + tx * 4];
      acc[0][0] = fmaf(a.x, b.x, acc[0][0]);
      acc[0][1] = fmaf(a.x, b.y, acc[0][1]);
      acc[0][2] = fmaf(a.x, b.z, acc[0][2]);
      acc[0][3] = fmaf(a.x, b.w, acc[0][3]);
      acc[1][0] = fmaf(a.y, b.x, acc[1][0]);
      acc[1][1] = fmaf(a.y, b.y, acc[1][1]);
      acc[1][2] = fmaf(a.y, b.z, acc[1][2]);
      acc[1][3] = fmaf(a.y, b.w, acc[1][3]);
      acc[2][0] = fmaf(a.z, b.x, acc[2][0]);
      acc[2][1] = fmaf(a.z, b.y, acc[2][1]);
      acc[2][2] = fmaf(a.z, b.z, acc[2][2]);
      acc[2][3] = fmaf(a.z, b.w, acc[2][3]);
      acc[3][0] = fmaf(a.w, b.x, acc[3][0]);
      acc[3][1] = fmaf(a.w, b.y, acc[3][1]);
      acc[3][2] = fmaf(a.w, b.z, acc[3][2]);
      acc[3][3] = fmaf(a.w, b.w, acc[3][3]);
    }

    #pragma unroll
    for (int r = 0; r < 4; ++r) {
      const int grow = row_base + ty * 4 + r;
      if (grow < nrows) {
        ushort4 o;
        o.x = f32_to_bf16(acc[r][0]);
        o.y = f32_to_bf16(acc[r][1]);
        o.z = f32_to_bf16(acc[r][2]);
        o.w = f32_to_bf16(acc[r][3]);
        *(ushort4*)(Y + (size_t)grow * DIM + tx * 4) = o;
      }
    }
    return;
  }

  // --------------------------- binning path ------------------------------
  uint2* sbuf = (uint2*)smem;                          // 32 KB
  unsigned short* sbk = (unsigned short*)(smem + 32768); // 8 KB -> 40960
  int* sh   = (int*)(smem + 40960);                    // NB_MAX ints -> 44088
  int* scnt = (int*)(smem + 44088);                    // NB_MAX ints -> 47216
  int* s_w  = (int*)(smem + 47232);                    // 9 ints

  const int tbase = (blockIdx.x - (PREP_GU + PREP_GI)) * TILE;
  const int total = min(TILE, NNZ_EDGES - tbase);

  int er[8], ec[8]; unsigned ev[8];
  #pragma unroll
  for (int k = 0; k < 8; ++k) {
    const int i = tbase + k * 512 + tid;
    if (i < NNZ_EDGES) {
      er[k] = rows[i];
      ec[k] = cols[i];
      ev[k] = __float_as_uint(vals[i]);
    } else {
      er[k] = -1; ec[k] = 0; ev[k] = 0;
    }
  }

#define BIN_PHASE(BKEXPR, PKEXPR, NB, CUR, OUT)                                \
  {                                                                            \
    for (int j = tid; j < (NB); j += 512) sh[j] = 0;                           \
    __syncthreads();                                                           \
    int bk[8]; unsigned pk[8];                                                 \
    _Pragma("unroll")                                                          \
    for (int k = 0; k < 8; ++k) {                                              \
      if (er[k] >= 0) {                                                        \
        bk[k] = (BKEXPR); pk[k] = (PKEXPR);                                    \
        atomicAdd(&sh[bk[k]], 1);                                              \
      } else { bk[k] = -1; pk[k] = 0; }                                        \
    }                                                                          \
    __syncthreads();                                                           \
    int carry = 0;                                                             \
    for (int cb = 0; cb < (NB); cb += 512) {                                   \
      const int idx = cb + tid;                                                \
      const int x = (idx < (NB)) ? sh[idx] : 0;                                \
      int incl = x;                                                            \
      _Pragma("unroll")                                                        \
      for (int d = 1; d < 64; d <<= 1) {                                       \
        int t = __shfl_up(incl, d);                                            \
        if (lane >= d) incl += t;                                              \
      }                                                                        \
      if (lane == 63) s_w[wid] = incl;                                         \
      __syncthreads();                                                         \
      if (tid == 0) {                                                          \
        int a = 0;                                                             \
        _Pragma("unroll")                                                      \
        for (int w = 0; w < 8; ++w) { const int t = s_w[w]; s_w[w] = a; a += t; } \
        s_w[8] = a;                                                            \
      }                                                                        \
      __syncthreads();                                                         \
      const int excl = carry + s_w[wid] + incl - x;                            \
      if (idx < (NB)) { scnt[idx] = x; sh[idx] = excl; }                       \
      carry += s_w[8];                                                         \
      __syncthreads();                                                         \
    }                                                                          \
    _Pragma("unroll")                                                          \
    for (int k = 0; k < 8; ++k) {                                              \
      if (bk[k] >= 0) {                                                        \
        const int p = atomicAdd(&sh[bk[k]], 1);                                \
        sbuf[p] = make_uint2(pk[k], ev[k]);                                    \
        sbk[p] = (unsigned short)bk[k];                                        \
      }                                                                        \
    }                                                                          \
    __syncthreads();                                                           \
    for (int idx = tid; idx < (NB); idx += 512) {                              \
      const int c = scnt[idx];                                                 \
      const int excl = sh[idx] - c;                                            \
      int g = 0;                                                               \
      if (c > 0) g = atomicAdd(&(CUR)[idx], c);                                \
      scnt[idx] = excl;                                                        \
      sh[idx] = idx * CAP + g;                                                 \
    }                                                                          \
    __syncthreads();                                                           \
    for (int p = tid; p < total; p += 512) {                                   \
      const int b = sbk[p];                                                    \
      (OUT)[sh[b] + (p - scnt[b])] = sbuf[p];                                  \
    }                                                                          \
    __syncthreads();                                                           \
  }

  BIN_PHASE(er[k] >> BSHIFT_U,
            ((unsigned)(er[k] & (BD_U - 1)) << 25) | ((unsigned)ec[k] << 7),
            NBU, cur_u, out_u)
  BIN_PHASE(ec[k] >> BSHIFT_I,
            ((unsigned)(ec[k] & (BD_I - 1)) << 25) | ((unsigned)er[k] << 7),
            NBI, cur_i, out_i)
#undef BIN_PHASE
}

// ---------------------------------------------------------------------------
// Fused fine-sort + SpMM + ReLU. One 512-thread block (8 waves) per coarse
// bucket. Register staging + LDS hist -> scan -> scatter -> per-row gather
// loop (lane = feature, byte-offset gather = 1 VALU, ILP-16).
// ---------------------------------------------------------------------------
__global__ __launch_bounds__(512) void sort_spmm_kernel(
    const uint2* __restrict__ bin_u, const int* __restrict__ cur_u,
    const unsigned short* __restrict__ xw_item, float* __restrict__ out_user,
    const uint2* __restrict__ bin_i, const int* __restrict__ cur_i,
    const unsigned short* __restrict__ xw_user, float* __restrict__ out_item) {
  __shared__ uint2 sbuf[CAP];     // 19.5 KB (sorted records)
  __shared__ int cnt[128];        // hist -> scatter cursor -> row end
  __shared__ int roff[128];       // row start
  __shared__ int s_w[2];
  const int tid = threadIdx.x;
  const int lane = tid & 63, wid = tid >> 6;

  const uint2* bin; const int* cur; const unsigned short* xw; float* out;
  int b, bd, ndst;
  if (blockIdx.x < NBU) {
    b = blockIdx.x; bd = BD_U; ndst = N_USERS;
    bin = bin_u; cur = cur_u; xw = xw_item; out = out_user;
  } else {
    b = blockIdx.x - NBU; bd = BD_I; ndst = N_ITEMS;
    bin = bin_i; cur = cur_i; xw = xw_user; out = out_item;
  }
  const int beg = b * CAP;
  const int n = min(cur[b], CAP);   // cursor holds the COUNT (offset-based)

  if (tid < bd) cnt[tid] = 0;
  __syncthreads();

  // Stage records in registers + LDS histogram of local dests.
  uint2 rg[5];
  #pragma unroll
  for (int k = 0; k < 5; ++k) {
    const int i = k * 512 + tid;
    if (i < n) {
      rg[k] = bin[beg + i];
      atomicAdd(&cnt[rg[k].x >> 25], 1);
    } else {
      rg[k] = make_uint2(0u, 0u);
    }
  }
  __syncthreads();

  // Exclusive scan of cnt[0..bd) in the first 128 threads (bd <= 128).
  int x = 0, incl = 0;
  if (tid < 128) {
    x = (tid < bd) ? cnt[tid] : 0;
    incl = x;
    #pragma unroll
    for (int d = 1; d < 64; d <<= 1) {
      int t = __shfl_up(incl, d);
      if (lane >= d) incl += t;
    }
    if (lane == 63) s_w[wid] = incl;
  }
  __syncthreads();
  if (tid == 0) {
    const int t0 = s_w[0];
    s_w[0] = 0;
    s_w[1] = t0;
  }
  __syncthreads();
  if (tid < 128) {
    const int excl = s_w[wid] + incl - x;
    if (tid < bd) {
      roff[tid] = excl;   // row start
      cnt[tid] = excl;    // scatter cursor (becomes row end after scatter)
    }
  }
  __syncthreads();

  // Scatter registers -> sorted LDS buffer.
  #pragma unroll
  for (int k = 0; k < 5; ++k) {
    const int i = k * 512 + tid;
    if (i < n) {
      const int p = atomicAdd(&cnt[rg[k].x >> 25], 1);
      sbuf[p] = rg[k];
    }
  }
  __syncthreads();

  // SpMM: wave w handles rows w, w+8, ... ; lane = feature; byte-offset gather.
  const char* __restrict__ xwb = (const char*)xw + lane * 2;
  for (int r = wid; r < bd; r += 8) {
    const int rb = roff[r], re = cnt[r];
    float acc = 0.f;
    int j = rb;
    for (; j + 16 <= re; j += 16) {
      uint2 e[16];
      #pragma unroll
      for (int q = 0; q < 16; ++q) e[q] = sbuf[j + q];   // LDS broadcast
      unsigned short h[16];
      #pragma unroll
      for (int q = 0; q < 16; ++q)
        h[q] = *(const unsigned short*)(xwb + (e[q].x & 0x01FFFF80u));
      #pragma unroll
      for (int q = 0; q < 16; ++q)
        acc = fmaf(__uint_as_float(e[q].y), bf16_to_f32(h[q]), acc);
    }
    for (; j + 8 <= re; j += 8) {
      uint2 e[8];
      #pragma unroll
      for (int q = 0; q < 8; ++q) e[q] = sbuf[j + q];
      unsigned short h[8];
      #pragma unroll
      for (int q = 0; q < 8; ++q)
        h[q] = *(const unsigned short*)(xwb + (e[q].x & 0x01FFFF80u));
      #pragma unroll
      for (int q = 0; q < 8; ++q)
        acc = fmaf(__uint_as_float(e[q].y), bf16_to_f32(h[q]), acc);
    }
    for (; j + 4 <= re; j += 4) {
      uint2 e[4];
      #pragma unroll
      for (int q = 0; q < 4; ++q) e[q] = sbuf[j + q];
      unsigned short h[4];
      #pragma unroll
      for (int q = 0; q < 4; ++q)
        h[q] = *(const unsigned short*)(xwb + (e[q].x & 0x01FFFF80u));
      #pragma unroll
      for (int q = 0; q < 4; ++q)
        acc = fmaf(__uint_as_float(e[q].y), bf16_to_f32(h[q]), acc);
    }
    for (; j < re; ++j) {
      const uint2 e = sbuf[j];
      acc = fmaf(__uint_as_float(e.y),
                 bf16_to_f32(*(const unsigned short*)(xwb + (e.x & 0x01FFFF80u))),
                 acc);
    }
    const int grow = b * bd + r;
    if (grow < ndst) out[(size_t)grow * DIM + lane] = fmaxf(acc, 0.f);
  }
}

extern "C" void kernel_launch(void* const* d_in, const int* in_sizes, int n_in,
                              void* d_out, int out_size, void* d_ws, size_t ws_size,
                              hipStream_t stream) {
  const float* user_x      = (const float*)d_in[0];
  const float* item_x      = (const float*)d_in[1];
  const float* user_weight = (const float*)d_in[2];
  const float* item_weight = (const float*)d_in[3];
  const int*   ui_rows     = (const int*)d_in[4];
  const int*   ui_cols     = (const int*)d_in[5];
  const float* ui_vals     = (const float*)d_in[6];

  float* out_user = (float*)d_out;
  float* out_item = (float*)d_out + (size_t)N_USERS * DIM;

  // ---- workspace layout (fixed-capacity bucket regions) ------------------
  unsigned short* xw_user = (unsigned short*)d_ws;               // 6.4M bf16
  unsigned short* xw_item = xw_user + (size_t)N_USERS * DIM;     // 3.2M bf16
  uint2* binA = (uint2*)(xw_item + (size_t)N_ITEMS * DIM);       // user buckets
  uint2* binB = binA + (size_t)NBU * CAP;                        // item buckets
  int*   cur_u = (int*)(binB + (size_t)NBI * CAP);               // NBU
  int*   cur_i = cur_u + NBU;                                    // NBI
  // total ~49.7 MB

  // 0. Zero offset-based bucket cursors (~6 KB).
  hipMemsetAsync(cur_u, 0, (NBU + NBI) * sizeof(int), stream);

  // 1. Merged GEMM + binning (independent work overlapped in one dispatch).
  prep_kernel<<<PREP_GU + PREP_GI + PREP_BIN, 512, 0, stream>>>(
      user_x, user_weight, xw_user, item_x, item_weight, xw_item,
      ui_rows, ui_cols, ui_vals, cur_u, cur_i, binA, binB);

  // 2. Fused fine-sort + SpMM + ReLU (one 512-thread block per bucket).
  sort_spmm_kernel<<<NBU + NBI, 512, 0, stream>>>(
      binA, cur_u, xw_item, out_user,
      binB, cur_i, xw_user, out_item);
}